// Round 1
// baseline (161.830 us; speedup 1.0000x reference)
//
#include <hip/hip_runtime.h>
#include <hip/hip_bf16.h>

#define H 4
#define C 32
#define CQ 128
#define NSEQ 256
#define HC 128   // H*C

typedef __bf16 bf16;
typedef __bf16 bf16x8 __attribute__((ext_vector_type(8)));
typedef __bf16 bf16x4 __attribute__((ext_vector_type(4)));
typedef float f32x4 __attribute__((ext_vector_type(4)));

#define MFMA16(a, b, c) __builtin_amdgcn_mfma_f32_16x16x32_bf16(a, b, c, 0, 0, 0)

// ---------------------------------------------------------------------------
// Dual projection: out1 = act1(x @ w1^T), out2 = act2(x @ w2^T)
// x: [M,128] f32, w: [128,128] f32 (row d = weights for output feature d)
// MODE 0: out1 *= 1/sqrt(32) (q), out2 = sigmoid (g). MODE 1: plain (k, v).
// ---------------------------------------------------------------------------
template <int MODE>
__global__ __launch_bounds__(256) void proj_dual(const float* __restrict__ x,
                                                 const float* __restrict__ w1,
                                                 const float* __restrict__ w2,
                                                 bf16* __restrict__ out1,
                                                 bf16* __restrict__ out2) {
    __shared__ bf16 xs[64][136];    // +8 pad -> 2-way bank alias (free)
    __shared__ bf16 w1s[128][136];
    __shared__ bf16 w2s[128][136];

    const int t = threadIdx.x;
    const int m0 = blockIdx.x * 64;

    // stage x tile (contiguous 64x128 f32)
    {
        const float4* src = (const float4*)(x + (size_t)m0 * CQ);
        for (int i = t; i < 64 * 128 / 4; i += 256) {
            float4 v = src[i];
            int row = (i * 4) >> 7, col = (i * 4) & 127;
            bf16x4 b = {(bf16)v.x, (bf16)v.y, (bf16)v.z, (bf16)v.w};
            *(bf16x4*)&xs[row][col] = b;
        }
        const float4* s1 = (const float4*)w1;
        const float4* s2 = (const float4*)w2;
        for (int i = t; i < 128 * 128 / 4; i += 256) {
            int row = (i * 4) >> 7, col = (i * 4) & 127;
            float4 v = s1[i];
            bf16x4 b = {(bf16)v.x, (bf16)v.y, (bf16)v.z, (bf16)v.w};
            *(bf16x4*)&w1s[row][col] = b;
            float4 u = s2[i];
            bf16x4 b2 = {(bf16)u.x, (bf16)u.y, (bf16)u.z, (bf16)u.w};
            *(bf16x4*)&w2s[row][col] = b2;
        }
    }
    __syncthreads();

    const int w = t >> 6;   // wave 0..3 -> 16 rows each
    const int l = t & 63;
    const int lr = l & 15;  // A/B row within 16-tile
    const int lg = l >> 4;  // k-group (8 contiguous k per lane)

    bf16x8 a[4];
    for (int ks = 0; ks < 4; ks++)
        a[ks] = *(const bf16x8*)&xs[w * 16 + lr][ks * 32 + lg * 8];

    f32x4 acc1[8], acc2[8];
    for (int nt = 0; nt < 8; nt++) { acc1[nt] = (f32x4)0.f; acc2[nt] = (f32x4)0.f; }

    for (int nt = 0; nt < 8; nt++) {
        for (int ks = 0; ks < 4; ks++) {
            bf16x8 b1 = *(const bf16x8*)&w1s[nt * 16 + lr][ks * 32 + lg * 8];
            acc1[nt] = MFMA16(a[ks], b1, acc1[nt]);
        }
        for (int ks = 0; ks < 4; ks++) {
            bf16x8 b2 = *(const bf16x8*)&w2s[nt * 16 + lr][ks * 32 + lg * 8];
            acc2[nt] = MFMA16(a[ks], b2, acc2[nt]);
        }
    }

    const float qscale = 0.17677669529663687f;  // 1/sqrt(32)
    for (int nt = 0; nt < 8; nt++) {
        for (int r = 0; r < 4; r++) {
            int row = m0 + w * 16 + lg * 4 + r;  // D: row=(l>>4)*4+r
            int col = nt * 16 + lr;              //    col=l&15
            float v1 = acc1[nt][r], v2 = acc2[nt][r];
            if (MODE == 0) {
                v1 *= qscale;
                v2 = 1.f / (1.f + __expf(-v2));
            }
            out1[(size_t)row * HC + col] = (bf16)v1;
            out2[(size_t)row * HC + col] = (bf16)v2;
        }
    }
}

// ---------------------------------------------------------------------------
// Attention per (qchunk, n1, h): 64 q-rows x 256 k, C=32.
// scores = q.k^T + pair_bias[h,q,k] + mask_bias[n1,k]; softmax over k; o = P.v
// o gated with g and written bf16 to o_ws [65536,128] head slice.
// ---------------------------------------------------------------------------
__global__ __launch_bounds__(256) void attn_kernel(const bf16* __restrict__ qw,
                                                   const bf16* __restrict__ kw,
                                                   const bf16* __restrict__ vw,
                                                   const bf16* __restrict__ gw,
                                                   const float* __restrict__ pair_bias,
                                                   const float* __restrict__ mask_bias,
                                                   bf16* __restrict__ ow) {
    const int qc = blockIdx.x;  // 0..3
    const int n1 = blockIdx.y;  // 0..255
    const int h = blockIdx.z;   // 0..3

    __shared__ bf16 klds[256][40];    // K slice [k][c], +8 pad
    __shared__ bf16 vts[32][264];     // V^T slice [c][k], +8 pad
    __shared__ bf16 ps[4][16][264];   // per-wave P tile [q][k]

    const int t = threadIdx.x;

    // stage K and V^T head slices for this n1
    {
        const size_t base = ((size_t)n1 * NSEQ) * HC + (size_t)h * C;
        for (int p = 0; p < 4; p++) {
            int row = p * 64 + (t >> 2);
            int ch = (t & 3) * 8;
            bf16x8 kv = *(const bf16x8*)&kw[base + (size_t)row * HC + ch];
            *(bf16x8*)&klds[row][ch] = kv;
            bf16x8 vv = *(const bf16x8*)&vw[base + (size_t)row * HC + ch];
            for (int j = 0; j < 8; j++) vts[ch + j][row] = vv[j];
        }
    }

    const int w = t >> 6;
    const int l = t & 63;
    const int lr = l & 15;
    const int lg = l >> 4;
    const int qbase = qc * 64 + w * 16;

    // Q fragment: A[q=lr][c = lg*8 + j]
    bf16x8 qf = *(const bf16x8*)&qw[((size_t)(n1 * NSEQ + qbase + lr)) * HC + h * C + lg * 8];

    __syncthreads();

    // scores: 16 k-tiles, one MFMA each (K-dim = C = 32)
    f32x4 s[16];
    for (int kt = 0; kt < 16; kt++) {
        bf16x8 kf = *(const bf16x8*)&klds[kt * 16 + lr][lg * 8];
        s[kt] = MFMA16(qf, kf, (f32x4)0.f);
    }

    // biases: lane holds (q = qbase + lg*4 + r, k = kt*16 + lr)
    const float* pb = pair_bias + (size_t)h * NSEQ * NSEQ;
    const float* mb = mask_bias + (size_t)n1 * NSEQ;
    for (int kt = 0; kt < 16; kt++) {
        int k = kt * 16 + lr;
        float m = mb[k];
        for (int r = 0; r < 4; r++) {
            int q = qbase + lg * 4 + r;
            s[kt][r] += pb[(size_t)q * NSEQ + k] + m;
        }
    }

    // softmax over k per row (16 lanes of a row-group + 16 per-lane values)
    float pinv[4];
    for (int r = 0; r < 4; r++) {
        float mx = s[0][r];
        for (int kt = 1; kt < 16; kt++) mx = fmaxf(mx, s[kt][r]);
        for (int m = 8; m >= 1; m >>= 1) mx = fmaxf(mx, __shfl_xor(mx, m, 64));
        float sum = 0.f;
        for (int kt = 0; kt < 16; kt++) {
            float e = __expf(s[kt][r] - mx);
            s[kt][r] = e;
            sum += e;
        }
        for (int m = 8; m >= 1; m >>= 1) sum += __shfl_xor(sum, m, 64);
        pinv[r] = 1.f / sum;
    }

    // P -> per-wave LDS (relayout for PV A-fragment); same-wave dep, no barrier
    for (int kt = 0; kt < 16; kt++)
        for (int r = 0; r < 4; r++)
            ps[w][lg * 4 + r][kt * 16 + lr] = (bf16)(s[kt][r] * pinv[r]);

    // PV: o[q][c], two c-tiles, 8 K-steps of 32
    f32x4 o[2];
    o[0] = (f32x4)0.f;
    o[1] = (f32x4)0.f;
    for (int kc = 0; kc < 8; kc++) {
        bf16x8 pf = *(const bf16x8*)&ps[w][lr][kc * 32 + lg * 8];
        for (int ct = 0; ct < 2; ct++) {
            bf16x8 vf = *(const bf16x8*)&vts[ct * 16 + lr][kc * 32 + lg * 8];
            o[ct] = MFMA16(pf, vf, o[ct]);
        }
    }

    // gate + store head slice
    for (int ct = 0; ct < 2; ct++) {
        for (int r = 0; r < 4; r++) {
            int q = qbase + lg * 4 + r;
            int c = ct * 16 + lr;
            size_t idx = ((size_t)(n1 * NSEQ + q)) * HC + (size_t)h * C + c;
            float g = (float)gw[idx];
            ow[idx] = (bf16)(o[ct][r] * g);
        }
    }
}

// ---------------------------------------------------------------------------
// Output projection: out[m, c] = sum_d og[m, d] * w_o[c, d]  (f32 out)
// ---------------------------------------------------------------------------
__global__ __launch_bounds__(256) void out_proj(const bf16* __restrict__ og,
                                                const float* __restrict__ wo,
                                                float* __restrict__ out) {
    __shared__ bf16 xs[64][136];
    __shared__ bf16 ws[128][136];
    const int t = threadIdx.x;
    const int m0 = blockIdx.x * 64;

    const bf16x8* src = (const bf16x8*)(og + (size_t)m0 * HC);
    for (int i = t; i < 64 * 128 / 8; i += 256) {
        bf16x8 v = src[i];
        int row = (i * 8) >> 7, col = (i * 8) & 127;
        *(bf16x8*)&xs[row][col] = v;
    }
    const float4* s1 = (const float4*)wo;
    for (int i = t; i < 128 * 128 / 4; i += 256) {
        float4 v = s1[i];
        int row = (i * 4) >> 7, col = (i * 4) & 127;
        bf16x4 b = {(bf16)v.x, (bf16)v.y, (bf16)v.z, (bf16)v.w};
        *(bf16x4*)&ws[row][col] = b;
    }
    __syncthreads();

    const int w = t >> 6, l = t & 63, lr = l & 15, lg = l >> 4;
    bf16x8 a[4];
    for (int ks = 0; ks < 4; ks++)
        a[ks] = *(const bf16x8*)&xs[w * 16 + lr][ks * 32 + lg * 8];

    f32x4 acc[8];
    for (int nt = 0; nt < 8; nt++) acc[nt] = (f32x4)0.f;
    for (int nt = 0; nt < 8; nt++)
        for (int ks = 0; ks < 4; ks++) {
            bf16x8 b = *(const bf16x8*)&ws[nt * 16 + lr][ks * 32 + lg * 8];
            acc[nt] = MFMA16(a[ks], b, acc[nt]);
        }

    for (int nt = 0; nt < 8; nt++)
        for (int r = 0; r < 4; r++)
            out[(size_t)(m0 + w * 16 + lg * 4 + r) * CQ + nt * 16 + lr] = acc[nt][r];
}

// ---------------------------------------------------------------------------
extern "C" void kernel_launch(void* const* d_in, const int* in_sizes, int n_in,
                              void* d_out, int out_size, void* d_ws, size_t ws_size,
                              hipStream_t stream) {
    const float* q_x = (const float*)d_in[0];
    const float* kv_x = (const float*)d_in[1];
    const float* mask_bias = (const float*)d_in[2];
    const float* pair_bias = (const float*)d_in[3];
    const float* w_q = (const float*)d_in[4];
    const float* w_k = (const float*)d_in[5];
    const float* w_v = (const float*)d_in[6];
    const float* w_g = (const float*)d_in[7];
    const float* w_o = (const float*)d_in[8];

    const size_t M = (size_t)NSEQ * NSEQ;  // 65536
    bf16* qws = (bf16*)d_ws;
    bf16* gws = qws + M * HC;
    bf16* kws = gws + M * HC;
    bf16* vws = kws + M * HC;
    bf16* ows = vws + M * HC;  // total 5 * 16 MB = 80 MB of d_ws

    proj_dual<0><<<dim3(1024), 256, 0, stream>>>(q_x, w_q, w_g, qws, gws);
    proj_dual<1><<<dim3(1024), 256, 0, stream>>>(kv_x, w_k, w_v, kws, vws);
    attn_kernel<<<dim3(4, 256, 4), 256, 0, stream>>>(qws, kws, vws, gws, pair_bias,
                                                     mask_bias, ows);
    out_proj<<<dim3(1024), 256, 0, stream>>>(ows, w_o, (float*)d_out);
}